// Round 3
// baseline (1390.787 us; speedup 1.0000x reference)
//
#include <hip/hip_runtime.h>
#include <cstdint>
#include <cmath>

// ---------------------------------------------------------------------------
// HawkBlock on MI355X (gfx950). Round 3.
// R2 post-mortem: gemm2 (dual-B, 128 acc regs) stuck at 2 blocks/CU (Occ 22%),
// 808 TF. This round: gemm2 -> per-B 128x64 tile (64 acc regs, LDS 32KB,
// lb(256,3) => 3 blocks/CU); gemm1 lb(256,3); single merged f2b kernel;
// scan processes 2 channels/thread (4B/lane loads).
//
// Dataflow (ws high-water 173 MB; d_out doubles as scratch):
//   h    = rmsnorm(x, ln1)                       -> ws[44..76)
//   xin  = h @ w_in^T            (raw bf16)      -> d_out
//   gate = sigmoid(h @ w_gate^T) (bf16)          -> ws[108..172)   [dual GEMM]
//   z    = a_param + xin @ w_a^T (fp16 logit)    -> ws[44..108)
//   y    = gate * scan(xin, sigmoid(z))          -> in-place over gate
//   xr   = x + y @ w_out^T       (fp32)          -> d_out (overwrites xin)
//   h2   = rmsnorm(xr, ln2)                      -> ws[44..76)
//   per half n of INTER:
//     m_n = silu(h2@w_mg_n^T) * (h2@w_mu_n^T)    -> ws[108..172)   [dual GEMM]
//     out += m_n @ w_md_n^T                      -> d_out in-place
// ---------------------------------------------------------------------------

typedef unsigned short u16;
typedef _Float16 f16;
typedef __bf16 bf16x8 __attribute__((ext_vector_type(8)));
typedef float  f32x4  __attribute__((ext_vector_type(4)));

#define BM 128
#define BN 128
#define BK 64

#define HID   1024
#define DREC  2048
#define INTER 4096
#define BT    16384   // B*T rows
#define TLEN  4096
#define NCHAN 8192    // B * DREC
#define CHUNK 256
#define NCH   16      // TLEN / CHUNK
#define NPAIR 4096    // NCHAN/2 channel pairs

__device__ __forceinline__ float b2f(u16 u) {
  union { unsigned int i; float f; } v; v.i = ((unsigned int)u) << 16; return v.f;
}
__device__ __forceinline__ u16 f2bf(float f) {  // RNE
  unsigned int u = __builtin_bit_cast(unsigned int, f);
  u += 0x7FFFu + ((u >> 16) & 1u);
  return (u16)(u >> 16);
}
__device__ __forceinline__ float sigm(float x) { return 1.f / (1.f + expf(-x)); }

typedef __attribute__((address_space(1))) void as1_void;
typedef __attribute__((address_space(3))) void as3_void;
__device__ __forceinline__ void async16(const void* g, void* l) {
  __builtin_amdgcn_global_load_lds((as1_void*)g, (as3_void*)l, 16, 0, 0);
}

// ---------------------------------------------------------------------------
// All 7 weight conversions in ONE kernel. Segment boundaries are compile-time
// block counts (all multiples of 256 float4s -> no intra-block straddle).
__global__ void f2b_all(const float* s0, const float* s1, const float* s2,
                        const float* s3, const float* s4, const float* s5,
                        const float* s6,
                        u16* d0, u16* d1, u16* d2, u16* d3, u16* d4, u16* d5,
                        u16* d6) {
  // block counts: 2048,2048,4096,2048,4096,4096,4096 (total 22528)
  int blk = blockIdx.x;
  const float* src; u16* dst; int rel;
  if      (blk < 2048)  { src = s0; dst = d0; rel = blk; }
  else if (blk < 4096)  { src = s1; dst = d1; rel = blk - 2048; }
  else if (blk < 8192)  { src = s2; dst = d2; rel = blk - 4096; }
  else if (blk < 10240) { src = s3; dst = d3; rel = blk - 8192; }
  else if (blk < 14336) { src = s4; dst = d4; rel = blk - 10240; }
  else if (blk < 18432) { src = s5; dst = d5; rel = blk - 14336; }
  else                  { src = s6; dst = d6; rel = blk - 18432; }
  int i = rel * 256 + threadIdx.x;
  float4 v = ((const float4*)src)[i];
  ushort4 o;
  o.x = f2bf(v.x); o.y = f2bf(v.y); o.z = f2bf(v.z); o.w = f2bf(v.w);
  ((ushort4*)dst)[i] = o;
}

// rmsnorm over rows of 1024 fp32, bf16 out. One 256-thread block per row.
__global__ void rmsnorm_kernel(const float* __restrict__ x, const float* __restrict__ w,
                               u16* __restrict__ out) {
  const int row = blockIdx.x;
  const int tid = threadIdx.x;
  float4 v = ((const float4*)(x + (size_t)row * HID))[tid];
  float ss = v.x * v.x + v.y * v.y + v.z * v.z + v.w * v.w;
#pragma unroll
  for (int o = 32; o > 0; o >>= 1) ss += __shfl_down(ss, o);
  __shared__ float red[4];
  const int lane = tid & 63, wv = tid >> 6;
  if (lane == 0) red[wv] = ss;
  __syncthreads();
  float tot = red[0] + red[1] + red[2] + red[3];
  float sc = rsqrtf(tot * (1.f / (float)HID) + 1e-6f);
  float4 wv4 = ((const float4*)w)[tid];
  ushort4 o;
  o.x = f2bf(v.x * sc * wv4.x); o.y = f2bf(v.y * sc * wv4.y);
  o.z = f2bf(v.z * sc * wv4.z); o.w = f2bf(v.w * sc * wv4.w);
  ((ushort4*)(out + (size_t)row * HID))[tid] = o;
}

// ---------------------------------------------------------------------------
// Single-B GEMM: C[M,N] = A[M,K] @ W[N,K]^T (rows strided ldA/ldW), fp32 acc.
enum { EPI_LOGIT = 0, EPI_ADDF = 1 };

template <int EPI>
__global__ __launch_bounds__(256, 3)
void gemm1(const u16* __restrict__ A, const u16* __restrict__ W,
           int K, int N, int ldA, int ldW,
           float* outf, f16* outz, const float* auxf) {
  __shared__ alignas(16) u16 sA[BM * BK];
  __shared__ alignas(16) u16 sB[BN * BK];

  const int tid  = threadIdx.x;
  const int lane = tid & 63;
  const int wv   = tid >> 6;
  const int wm   = wv & 1;
  const int wn   = wv >> 1;
  const int lm   = lane & 15;
  const int quad = lane >> 4;

  const int row0 = blockIdx.x * BM;
  const int col0 = blockIdx.y * BN;

  f32x4 acc[4][4];
#pragma unroll
  for (int i = 0; i < 4; ++i)
#pragma unroll
    for (int j = 0; j < 4; ++j) acc[i][j] = (f32x4)0.f;

  for (int k0 = 0; k0 < K; k0 += BK) {
#pragma unroll
    for (int i = 0; i < 4; ++i) {
      int p = i * 256 + tid;
      int r = p >> 3;
      int sg = (p & 7) ^ (r & 7);
      async16(A + (size_t)(row0 + r) * ldA + (k0 + sg * 8), (char*)sA + p * 16);
    }
#pragma unroll
    for (int i = 0; i < 4; ++i) {
      int p = i * 256 + tid;
      int r = p >> 3;
      int sg = (p & 7) ^ (r & 7);
      async16(W + (size_t)(col0 + r) * ldW + (k0 + sg * 8), (char*)sB + p * 16);
    }
    __syncthreads();

#pragma unroll
    for (int h = 0; h < 2; ++h) {
      bf16x8 af[4], bf[4];
#pragma unroll
      for (int mi = 0; mi < 4; ++mi) {
        int r = wm * 64 + mi * 16 + lm;
        af[mi] = ((const bf16x8*)sA)[r * 8 + ((h * 4 + quad) ^ (r & 7))];
      }
#pragma unroll
      for (int ni = 0; ni < 4; ++ni) {
        int c = wn * 64 + ni * 16 + lm;
        bf[ni] = ((const bf16x8*)sB)[c * 8 + ((h * 4 + quad) ^ (c & 7))];
      }
#pragma unroll
      for (int mi = 0; mi < 4; ++mi)
#pragma unroll
        for (int ni = 0; ni < 4; ++ni)
          acc[mi][ni] = __builtin_amdgcn_mfma_f32_16x16x32_bf16(af[mi], bf[ni], acc[mi][ni], 0, 0, 0);
    }
    __syncthreads();
  }

  // C/D layout: col = lane&15, row = quad*4 + reg  (m89/m91-verified)
#pragma unroll
  for (int mi = 0; mi < 4; ++mi) {
    const int rbase = row0 + wm * 64 + mi * 16 + quad * 4;
#pragma unroll
    for (int ni = 0; ni < 4; ++ni) {
      const int cg = col0 + wn * 64 + ni * 16 + lm;
      f32x4 v = acc[mi][ni];
#pragma unroll
      for (int rr = 0; rr < 4; ++rr) {
        size_t idx = (size_t)(rbase + rr) * N + cg;
        float t = v[rr];
        if constexpr (EPI == EPI_LOGIT) {
          outz[idx] = (f16)(t + auxf[cg]);      // pre-sigmoid logit, fp16
        } else {
          outf[idx] = t + auxf[idx];            // residual add; auxf may == outf
        }
      }
    }
  }
}

// ---------------------------------------------------------------------------
// Dual-B GEMM, round-3 shape: per-B tile 128x64 (block computes C0 and C1,
// each 128x64). Wave tile 64x32 per matrix -> acc 2*(4x2)*4 = 64 regs.
// LDS: A 16KB + B0 8KB + B1 8KB = 32KB -> with lb(256,3): 3 blocks/CU.
enum { EPI2_XG = 0, EPI2_SM = 1 };

template <int EPI>
__global__ __launch_bounds__(256, 3)
void gemm2(const u16* __restrict__ A, const u16* __restrict__ W0,
           const u16* __restrict__ W1,
           int K, int N, int ldA, int ldW,
           u16* out0, u16* out1) {
  __shared__ alignas(16) u16 sA[BM * BK];     // 128 x 64
  __shared__ alignas(16) u16 sB0[64 * BK];    // 64 x 64
  __shared__ alignas(16) u16 sB1[64 * BK];

  const int tid  = threadIdx.x;
  const int lane = tid & 63;
  const int wv   = tid >> 6;
  const int wm   = wv & 1;   // row half (64 rows)
  const int wn   = wv >> 1;  // col half (32 cols per matrix)
  const int lm   = lane & 15;
  const int quad = lane >> 4;

  const int row0 = blockIdx.x * BM;
  const int col0 = blockIdx.y * 64;

  f32x4 acc0[4][2], acc1[4][2];
#pragma unroll
  for (int i = 0; i < 4; ++i)
#pragma unroll
    for (int j = 0; j < 2; ++j) { acc0[i][j] = (f32x4)0.f; acc1[i][j] = (f32x4)0.f; }

  for (int k0 = 0; k0 < K; k0 += BK) {
#pragma unroll
    for (int i = 0; i < 4; ++i) {             // A: 1024 segments of 16B
      int p = i * 256 + tid;
      int r = p >> 3;
      int sg = (p & 7) ^ (r & 7);
      async16(A + (size_t)(row0 + r) * ldA + (k0 + sg * 8), (char*)sA + p * 16);
    }
#pragma unroll
    for (int i = 0; i < 2; ++i) {             // B0/B1: 512 segments each
      int p = i * 256 + tid;
      int r = p >> 3;
      int sg = (p & 7) ^ (r & 7);
      size_t go = (size_t)(col0 + r) * ldW + (k0 + sg * 8);
      async16(W0 + go, (char*)sB0 + p * 16);
      async16(W1 + go, (char*)sB1 + p * 16);
    }
    __syncthreads();

#pragma unroll
    for (int h = 0; h < 2; ++h) {
      bf16x8 af[4], b0[2], b1[2];
#pragma unroll
      for (int mi = 0; mi < 4; ++mi) {
        int r = wm * 64 + mi * 16 + lm;
        af[mi] = ((const bf16x8*)sA)[r * 8 + ((h * 4 + quad) ^ (r & 7))];
      }
#pragma unroll
      for (int ni = 0; ni < 2; ++ni) {
        int c = wn * 32 + ni * 16 + lm;
        int o = c * 8 + ((h * 4 + quad) ^ (c & 7));
        b0[ni] = ((const bf16x8*)sB0)[o];
        b1[ni] = ((const bf16x8*)sB1)[o];
      }
#pragma unroll
      for (int mi = 0; mi < 4; ++mi)
#pragma unroll
        for (int ni = 0; ni < 2; ++ni) {
          acc0[mi][ni] = __builtin_amdgcn_mfma_f32_16x16x32_bf16(af[mi], b0[ni], acc0[mi][ni], 0, 0, 0);
          acc1[mi][ni] = __builtin_amdgcn_mfma_f32_16x16x32_bf16(af[mi], b1[ni], acc1[mi][ni], 0, 0, 0);
        }
    }
    __syncthreads();
  }

#pragma unroll
  for (int mi = 0; mi < 4; ++mi) {
    const int rbase = row0 + wm * 64 + mi * 16 + quad * 4;
#pragma unroll
    for (int ni = 0; ni < 2; ++ni) {
      const int cg = col0 + wn * 32 + ni * 16 + lm;
#pragma unroll
      for (int rr = 0; rr < 4; ++rr) {
        size_t idx = (size_t)(rbase + rr) * N + cg;
        float v0 = acc0[mi][ni][rr];
        float v1 = acc1[mi][ni][rr];
        if constexpr (EPI == EPI2_XG) {
          out0[idx] = f2bf(v0);                 // xin raw
          out1[idx] = f2bf(sigm(v1));           // gate
        } else {
          out0[idx] = f2bf(v0 * sigm(v0) * v1); // m = silu(g) * u
        }
      }
    }
  }
}

// ---------------------------------------------------------------------------
// Chunked scan, 2 channels per thread (4B/lane loads).
// a_t = sigmoid(z_t); h_t = a_t h_{t-1} + sqrt(1-a_t^2+1e-8) x_t
__global__ void scan_phase1(const f16* __restrict__ z, const u16* __restrict__ xin,
                            float2* __restrict__ ch_h, float2* __restrict__ ch_p) {
  int gtid = blockIdx.x * 256 + threadIdx.x;   // 16 chunks x 4096 pairs
  int c = gtid >> 12;
  int pair = gtid & (NPAIR - 1);
  int b = pair >> 10;                          // DREC/2 = 1024 pairs per batch
  int d = (pair & 1023) * 2;
  size_t base = ((size_t)b * TLEN + (size_t)c * CHUNK) * DREC + d;
  float2 h = {0.f, 0.f}, P = {1.f, 1.f};
#pragma unroll 8
  for (int t = 0; t < CHUNK; ++t) {
    size_t i = base + (size_t)t * DREC;
    f16 z2[2]; *(uint32_t*)z2 = *(const uint32_t*)(z + i);
    u16 x2[2]; *(uint32_t*)x2 = *(const uint32_t*)(xin + i);
    float a0 = sigm((float)z2[0]), a1 = sigm((float)z2[1]);
    h.x = a0 * h.x + sqrtf(1.f - a0 * a0 + 1e-8f) * b2f(x2[0]);
    h.y = a1 * h.y + sqrtf(1.f - a1 * a1 + 1e-8f) * b2f(x2[1]);
    P.x *= a0; P.y *= a1;
  }
  ch_h[gtid] = h;
  ch_p[gtid] = P;
}

__global__ void scan_phase2(float2* __restrict__ ch_h, const float2* __restrict__ ch_p) {
  int pair = blockIdx.x * 256 + threadIdx.x;   // 4096 pairs
  float2 H = {0.f, 0.f};
#pragma unroll
  for (int c = 0; c < NCH; ++c) {
    int i = c * NPAIR + pair;
    float2 he = ch_h[i];
    float2 P  = ch_p[i];
    ch_h[i] = H;          // carry-in for this chunk
    H.x = he.x + P.x * H.x;
    H.y = he.y + P.y * H.y;
  }
}

// Phase 3: rescan with carry-in; y = gate*h written IN PLACE over gate.
__global__ void scan_phase3(const f16* __restrict__ z, const u16* __restrict__ xin,
                            u16* gate_y, const float2* __restrict__ ch_h) {
  int gtid = blockIdx.x * 256 + threadIdx.x;
  int c = gtid >> 12;
  int pair = gtid & (NPAIR - 1);
  int b = pair >> 10;
  int d = (pair & 1023) * 2;
  size_t base = ((size_t)b * TLEN + (size_t)c * CHUNK) * DREC + d;
  float2 h = ch_h[gtid];
#pragma unroll 8
  for (int t = 0; t < CHUNK; ++t) {
    size_t i = base + (size_t)t * DREC;
    f16 z2[2]; *(uint32_t*)z2 = *(const uint32_t*)(z + i);
    u16 x2[2]; *(uint32_t*)x2 = *(const uint32_t*)(xin + i);
    u16 g2[2]; *(uint32_t*)g2 = *(const uint32_t*)(gate_y + i);
    float a0 = sigm((float)z2[0]), a1 = sigm((float)z2[1]);
    h.x = a0 * h.x + sqrtf(1.f - a0 * a0 + 1e-8f) * b2f(x2[0]);
    h.y = a1 * h.y + sqrtf(1.f - a1 * a1 + 1e-8f) * b2f(x2[1]);
    u16 o2[2];
    o2[0] = f2bf(b2f(g2[0]) * h.x);
    o2[1] = f2bf(b2f(g2[1]) * h.y);
    *(uint32_t*)(gate_y + i) = *(uint32_t*)o2;
  }
}

// ---------------------------------------------------------------------------
extern "C" void kernel_launch(void* const* d_in, const int* in_sizes, int n_in,
                              void* d_out, int out_size, void* d_ws, size_t ws_size,
                              hipStream_t stream) {
  const float* x      = (const float*)d_in[0];
  const float* ln1    = (const float*)d_in[1];
  const float* ln2    = (const float*)d_in[2];
  const float* w_in   = (const float*)d_in[3];
  const float* w_gate = (const float*)d_in[4];
  const float* a_par  = (const float*)d_in[5];
  const float* w_a    = (const float*)d_in[6];
  const float* w_out  = (const float*)d_in[7];
  const float* w_mg   = (const float*)d_in[8];
  const float* w_mu   = (const float*)d_in[9];
  const float* w_md   = (const float*)d_in[10];
  float* out = (float*)d_out;
  char* ws = (char*)d_ws;

  const size_t MB = 1024ull * 1024ull;
  // bf16 weights: 0..44 MB
  u16* wb_in  = (u16*)(ws + 0 * MB);    // 4 MB
  u16* wb_gt  = (u16*)(ws + 4 * MB);    // 4 MB
  u16* wb_a   = (u16*)(ws + 8 * MB);    // 8 MB
  u16* wb_out = (u16*)(ws + 16 * MB);   // 4 MB
  u16* wb_mg  = (u16*)(ws + 20 * MB);   // 8 MB
  u16* wb_mu  = (u16*)(ws + 28 * MB);   // 8 MB
  u16* wb_md  = (u16*)(ws + 36 * MB);   // 8 MB
  // activations (time-multiplexed)
  u16* hbuf  = (u16*)(ws + 44 * MB);    // 32 MB: h, later h2
  f16* zbuf  = (f16*)(ws + 44 * MB);    // 64 MB: a-logits (over dead h)
  u16* gateb = (u16*)(ws + 108 * MB);   // 64 MB: gate -> y -> dead
  u16* mbuf  = (u16*)(ws + 108 * MB);   // 64 MB: mlp half (after y dead)
  float2* chh = (float2*)(ws + 172 * MB);              // 512 KB
  float2* chp = (float2*)(ws + 172 * MB + 512 * 1024); // 512 KB
  u16* xinb = (u16*)d_out;              // d_out as scratch: xin, then xr
  // high-water: 173 MB of ws

  // 1) all weights -> bf16 in one launch
  f2b_all<<<22528, 256, 0, stream>>>(w_in, w_gate, w_a, w_out, w_mg, w_mu, w_md,
                                     wb_in, wb_gt, wb_a, wb_out, wb_mg, wb_mu, wb_md);

  // 2) h = rmsnorm(x, ln1)
  rmsnorm_kernel<<<BT, 256, 0, stream>>>(x, ln1, hbuf);

  // 3) fused: xin = h@w_in^T (raw, -> d_out), gate = sigmoid(h@w_gate^T)
  gemm2<EPI2_XG><<<dim3(BT / BM, DREC / 64), 256, 0, stream>>>(
      hbuf, wb_in, wb_gt, HID, DREC, HID, HID, xinb, gateb);

  // 4) z = a_param + xin@w_a^T  (fp16 logits)
  gemm1<EPI_LOGIT><<<dim3(BT / BM, DREC / BN), 256, 0, stream>>>(
      xinb, wb_a, DREC, DREC, DREC, DREC, nullptr, zbuf, a_par);

  // 5) chunked scan; y = gate*h in place over gate
  scan_phase1<<<NCH * NPAIR / 256, 256, 0, stream>>>(zbuf, xinb, chh, chp);
  scan_phase2<<<NPAIR / 256, 256, 0, stream>>>(chh, chp);
  scan_phase3<<<NCH * NPAIR / 256, 256, 0, stream>>>(zbuf, xinb, gateb, chh);

  // 6) xr = x + y@w_out^T  -> d_out (xin dead)
  gemm1<EPI_ADDF><<<dim3(BT / BM, HID / BN), 256, 0, stream>>>(
      gateb, wb_out, DREC, HID, DREC, DREC, out, nullptr, x);

  // 7) h2 = rmsnorm(xr, ln2)
  rmsnorm_kernel<<<BT, 256, 0, stream>>>(out, ln2, hbuf);

  // 8) MLP in two INTER halves; down-GEMM accumulates into d_out in place
  for (int half = 0; half < 2; ++half) {
    const u16* wmg_h = wb_mg + (size_t)half * 2048 * HID;
    const u16* wmu_h = wb_mu + (size_t)half * 2048 * HID;
    const u16* wmd_h = wb_md + (size_t)half * 2048;      // column slice, ldW=INTER
    gemm2<EPI2_SM><<<dim3(BT / BM, 2048 / 64), 256, 0, stream>>>(
        hbuf, wmg_h, wmu_h, HID, 2048, HID, HID, mbuf, nullptr);
    gemm1<EPI_ADDF><<<dim3(BT / BM, HID / BN), 256, 0, stream>>>(
        mbuf, wmd_h, 2048, HID, 2048, INTER, out, nullptr, out);
  }
}

// Round 4
// 1166.149 us; speedup vs baseline: 1.1926x; 1.1926x over previous
//
#include <hip/hip_runtime.h>
#include <cstdint>
#include <cmath>

// ---------------------------------------------------------------------------
// HawkBlock on MI355X (gfx950). Round 4.
// R3 post-mortem: scan w/ 2ch/thread + NCH=16 -> only 256 blocks (1 blk/CU,
// Occ 11%) -> latency-bound, 330 us scan. Fix: NCH=64, CHUNK=64 -> 1024
// blocks (4 blk/CU, 16 waves/CU) keeping 4B/lane vector loads. chh/chp (2MB
// each) overlay the dead wb_in/wb_gt region (only read in step 3, before the
// scan) so ws high-water stays at the known-safe 173 MB.
// GEMM structure unchanged from R3 (measured ~neutral vs R2).
//
// Dataflow (d_out doubles as scratch):
//   h    = rmsnorm(x, ln1)                       -> ws[44..76)
//   xin  = h @ w_in^T            (raw bf16)      -> d_out
//   gate = sigmoid(h @ w_gate^T) (bf16)          -> ws[108..172)   [dual GEMM]
//   z    = a_param + xin @ w_a^T (fp16 logit)    -> ws[44..108)
//   y    = gate * scan(xin, sigmoid(z))          -> in-place over gate
//   xr   = x + y @ w_out^T       (fp32)          -> d_out (overwrites xin)
//   h2   = rmsnorm(xr, ln2)                      -> ws[44..76)
//   per half n of INTER:
//     m_n = silu(h2@w_mg_n^T) * (h2@w_mu_n^T)    -> ws[108..172)   [dual GEMM]
//     out += m_n @ w_md_n^T                      -> d_out in-place
// ---------------------------------------------------------------------------

typedef unsigned short u16;
typedef _Float16 f16;
typedef __bf16 bf16x8 __attribute__((ext_vector_type(8)));
typedef float  f32x4  __attribute__((ext_vector_type(4)));

#define BM 128
#define BN 128
#define BK 64

#define HID   1024
#define DREC  2048
#define INTER 4096
#define BT    16384   // B*T rows
#define TLEN  4096
#define NCHAN 8192    // B * DREC
#define CHUNK 64
#define NCH   64      // TLEN / CHUNK
#define NPAIR 4096    // NCHAN/2 channel pairs

__device__ __forceinline__ float b2f(u16 u) {
  union { unsigned int i; float f; } v; v.i = ((unsigned int)u) << 16; return v.f;
}
__device__ __forceinline__ u16 f2bf(float f) {  // RNE
  unsigned int u = __builtin_bit_cast(unsigned int, f);
  u += 0x7FFFu + ((u >> 16) & 1u);
  return (u16)(u >> 16);
}
__device__ __forceinline__ float sigm(float x) { return 1.f / (1.f + expf(-x)); }

typedef __attribute__((address_space(1))) void as1_void;
typedef __attribute__((address_space(3))) void as3_void;
__device__ __forceinline__ void async16(const void* g, void* l) {
  __builtin_amdgcn_global_load_lds((as1_void*)g, (as3_void*)l, 16, 0, 0);
}

// ---------------------------------------------------------------------------
// All 7 weight conversions in ONE kernel. Segment boundaries are compile-time
// block counts (all multiples of 256 float4s -> no intra-block straddle).
__global__ void f2b_all(const float* s0, const float* s1, const float* s2,
                        const float* s3, const float* s4, const float* s5,
                        const float* s6,
                        u16* d0, u16* d1, u16* d2, u16* d3, u16* d4, u16* d5,
                        u16* d6) {
  // block counts: 2048,2048,4096,2048,4096,4096,4096 (total 22528)
  int blk = blockIdx.x;
  const float* src; u16* dst; int rel;
  if      (blk < 2048)  { src = s0; dst = d0; rel = blk; }
  else if (blk < 4096)  { src = s1; dst = d1; rel = blk - 2048; }
  else if (blk < 8192)  { src = s2; dst = d2; rel = blk - 4096; }
  else if (blk < 10240) { src = s3; dst = d3; rel = blk - 8192; }
  else if (blk < 14336) { src = s4; dst = d4; rel = blk - 10240; }
  else if (blk < 18432) { src = s5; dst = d5; rel = blk - 14336; }
  else                  { src = s6; dst = d6; rel = blk - 18432; }
  int i = rel * 256 + threadIdx.x;
  float4 v = ((const float4*)src)[i];
  ushort4 o;
  o.x = f2bf(v.x); o.y = f2bf(v.y); o.z = f2bf(v.z); o.w = f2bf(v.w);
  ((ushort4*)dst)[i] = o;
}

// rmsnorm over rows of 1024 fp32, bf16 out. One 256-thread block per row.
__global__ void rmsnorm_kernel(const float* __restrict__ x, const float* __restrict__ w,
                               u16* __restrict__ out) {
  const int row = blockIdx.x;
  const int tid = threadIdx.x;
  float4 v = ((const float4*)(x + (size_t)row * HID))[tid];
  float ss = v.x * v.x + v.y * v.y + v.z * v.z + v.w * v.w;
#pragma unroll
  for (int o = 32; o > 0; o >>= 1) ss += __shfl_down(ss, o);
  __shared__ float red[4];
  const int lane = tid & 63, wv = tid >> 6;
  if (lane == 0) red[wv] = ss;
  __syncthreads();
  float tot = red[0] + red[1] + red[2] + red[3];
  float sc = rsqrtf(tot * (1.f / (float)HID) + 1e-6f);
  float4 wv4 = ((const float4*)w)[tid];
  ushort4 o;
  o.x = f2bf(v.x * sc * wv4.x); o.y = f2bf(v.y * sc * wv4.y);
  o.z = f2bf(v.z * sc * wv4.z); o.w = f2bf(v.w * sc * wv4.w);
  ((ushort4*)(out + (size_t)row * HID))[tid] = o;
}

// ---------------------------------------------------------------------------
// Single-B GEMM: C[M,N] = A[M,K] @ W[N,K]^T (rows strided ldA/ldW), fp32 acc.
enum { EPI_LOGIT = 0, EPI_ADDF = 1 };

template <int EPI>
__global__ __launch_bounds__(256, 3)
void gemm1(const u16* __restrict__ A, const u16* __restrict__ W,
           int K, int N, int ldA, int ldW,
           float* outf, f16* outz, const float* auxf) {
  __shared__ alignas(16) u16 sA[BM * BK];
  __shared__ alignas(16) u16 sB[BN * BK];

  const int tid  = threadIdx.x;
  const int lane = tid & 63;
  const int wv   = tid >> 6;
  const int wm   = wv & 1;
  const int wn   = wv >> 1;
  const int lm   = lane & 15;
  const int quad = lane >> 4;

  const int row0 = blockIdx.x * BM;
  const int col0 = blockIdx.y * BN;

  f32x4 acc[4][4];
#pragma unroll
  for (int i = 0; i < 4; ++i)
#pragma unroll
    for (int j = 0; j < 4; ++j) acc[i][j] = (f32x4)0.f;

  for (int k0 = 0; k0 < K; k0 += BK) {
#pragma unroll
    for (int i = 0; i < 4; ++i) {
      int p = i * 256 + tid;
      int r = p >> 3;
      int sg = (p & 7) ^ (r & 7);
      async16(A + (size_t)(row0 + r) * ldA + (k0 + sg * 8), (char*)sA + p * 16);
    }
#pragma unroll
    for (int i = 0; i < 4; ++i) {
      int p = i * 256 + tid;
      int r = p >> 3;
      int sg = (p & 7) ^ (r & 7);
      async16(W + (size_t)(col0 + r) * ldW + (k0 + sg * 8), (char*)sB + p * 16);
    }
    __syncthreads();

#pragma unroll
    for (int h = 0; h < 2; ++h) {
      bf16x8 af[4], bf[4];
#pragma unroll
      for (int mi = 0; mi < 4; ++mi) {
        int r = wm * 64 + mi * 16 + lm;
        af[mi] = ((const bf16x8*)sA)[r * 8 + ((h * 4 + quad) ^ (r & 7))];
      }
#pragma unroll
      for (int ni = 0; ni < 4; ++ni) {
        int c = wn * 64 + ni * 16 + lm;
        bf[ni] = ((const bf16x8*)sB)[c * 8 + ((h * 4 + quad) ^ (c & 7))];
      }
#pragma unroll
      for (int mi = 0; mi < 4; ++mi)
#pragma unroll
        for (int ni = 0; ni < 4; ++ni)
          acc[mi][ni] = __builtin_amdgcn_mfma_f32_16x16x32_bf16(af[mi], bf[ni], acc[mi][ni], 0, 0, 0);
    }
    __syncthreads();
  }

  // C/D layout: col = lane&15, row = quad*4 + reg  (m89/m91-verified)
#pragma unroll
  for (int mi = 0; mi < 4; ++mi) {
    const int rbase = row0 + wm * 64 + mi * 16 + quad * 4;
#pragma unroll
    for (int ni = 0; ni < 4; ++ni) {
      const int cg = col0 + wn * 64 + ni * 16 + lm;
      f32x4 v = acc[mi][ni];
#pragma unroll
      for (int rr = 0; rr < 4; ++rr) {
        size_t idx = (size_t)(rbase + rr) * N + cg;
        float t = v[rr];
        if constexpr (EPI == EPI_LOGIT) {
          outz[idx] = (f16)(t + auxf[cg]);      // pre-sigmoid logit, fp16
        } else {
          outf[idx] = t + auxf[idx];            // residual add; auxf may == outf
        }
      }
    }
  }
}

// ---------------------------------------------------------------------------
// Dual-B GEMM: per-B tile 128x64, wave tile 64x32 per matrix, acc 64 regs,
// LDS 32KB, lb(256,3).
enum { EPI2_XG = 0, EPI2_SM = 1 };

template <int EPI>
__global__ __launch_bounds__(256, 3)
void gemm2(const u16* __restrict__ A, const u16* __restrict__ W0,
           const u16* __restrict__ W1,
           int K, int N, int ldA, int ldW,
           u16* out0, u16* out1) {
  __shared__ alignas(16) u16 sA[BM * BK];     // 128 x 64
  __shared__ alignas(16) u16 sB0[64 * BK];    // 64 x 64
  __shared__ alignas(16) u16 sB1[64 * BK];

  const int tid  = threadIdx.x;
  const int lane = tid & 63;
  const int wv   = tid >> 6;
  const int wm   = wv & 1;   // row half (64 rows)
  const int wn   = wv >> 1;  // col half (32 cols per matrix)
  const int lm   = lane & 15;
  const int quad = lane >> 4;

  const int row0 = blockIdx.x * BM;
  const int col0 = blockIdx.y * 64;

  f32x4 acc0[4][2], acc1[4][2];
#pragma unroll
  for (int i = 0; i < 4; ++i)
#pragma unroll
    for (int j = 0; j < 2; ++j) { acc0[i][j] = (f32x4)0.f; acc1[i][j] = (f32x4)0.f; }

  for (int k0 = 0; k0 < K; k0 += BK) {
#pragma unroll
    for (int i = 0; i < 4; ++i) {             // A: 1024 segments of 16B
      int p = i * 256 + tid;
      int r = p >> 3;
      int sg = (p & 7) ^ (r & 7);
      async16(A + (size_t)(row0 + r) * ldA + (k0 + sg * 8), (char*)sA + p * 16);
    }
#pragma unroll
    for (int i = 0; i < 2; ++i) {             // B0/B1: 512 segments each
      int p = i * 256 + tid;
      int r = p >> 3;
      int sg = (p & 7) ^ (r & 7);
      size_t go = (size_t)(col0 + r) * ldW + (k0 + sg * 8);
      async16(W0 + go, (char*)sB0 + p * 16);
      async16(W1 + go, (char*)sB1 + p * 16);
    }
    __syncthreads();

#pragma unroll
    for (int h = 0; h < 2; ++h) {
      bf16x8 af[4], b0[2], b1[2];
#pragma unroll
      for (int mi = 0; mi < 4; ++mi) {
        int r = wm * 64 + mi * 16 + lm;
        af[mi] = ((const bf16x8*)sA)[r * 8 + ((h * 4 + quad) ^ (r & 7))];
      }
#pragma unroll
      for (int ni = 0; ni < 2; ++ni) {
        int c = wn * 32 + ni * 16 + lm;
        int o = c * 8 + ((h * 4 + quad) ^ (c & 7));
        b0[ni] = ((const bf16x8*)sB0)[o];
        b1[ni] = ((const bf16x8*)sB1)[o];
      }
#pragma unroll
      for (int mi = 0; mi < 4; ++mi)
#pragma unroll
        for (int ni = 0; ni < 2; ++ni) {
          acc0[mi][ni] = __builtin_amdgcn_mfma_f32_16x16x32_bf16(af[mi], b0[ni], acc0[mi][ni], 0, 0, 0);
          acc1[mi][ni] = __builtin_amdgcn_mfma_f32_16x16x32_bf16(af[mi], b1[ni], acc1[mi][ni], 0, 0, 0);
        }
    }
    __syncthreads();
  }

#pragma unroll
  for (int mi = 0; mi < 4; ++mi) {
    const int rbase = row0 + wm * 64 + mi * 16 + quad * 4;
#pragma unroll
    for (int ni = 0; ni < 2; ++ni) {
      const int cg = col0 + wn * 32 + ni * 16 + lm;
#pragma unroll
      for (int rr = 0; rr < 4; ++rr) {
        size_t idx = (size_t)(rbase + rr) * N + cg;
        float v0 = acc0[mi][ni][rr];
        float v1 = acc1[mi][ni][rr];
        if constexpr (EPI == EPI2_XG) {
          out0[idx] = f2bf(v0);                 // xin raw
          out1[idx] = f2bf(sigm(v1));           // gate
        } else {
          out0[idx] = f2bf(v0 * sigm(v0) * v1); // m = silu(g) * u
        }
      }
    }
  }
}

// ---------------------------------------------------------------------------
// Chunked scan, 2 channels/thread, 64 chunks of 64 steps -> 1024 blocks.
// a_t = sigmoid(z_t); h_t = a_t h_{t-1} + sqrt(1-a_t^2+1e-8) x_t
__global__ void scan_phase1(const f16* __restrict__ z, const u16* __restrict__ xin,
                            float2* __restrict__ ch_h, float2* __restrict__ ch_p) {
  int gtid = blockIdx.x * 256 + threadIdx.x;   // 64 chunks x 4096 pairs
  int c = gtid >> 12;
  int pair = gtid & (NPAIR - 1);
  int b = pair >> 10;                          // DREC/2 = 1024 pairs per batch
  int d = (pair & 1023) * 2;
  size_t base = ((size_t)b * TLEN + (size_t)c * CHUNK) * DREC + d;
  float2 h = {0.f, 0.f}, P = {1.f, 1.f};
#pragma unroll 8
  for (int t = 0; t < CHUNK; ++t) {
    size_t i = base + (size_t)t * DREC;
    f16 z2[2]; *(uint32_t*)z2 = *(const uint32_t*)(z + i);
    u16 x2[2]; *(uint32_t*)x2 = *(const uint32_t*)(xin + i);
    float a0 = sigm((float)z2[0]), a1 = sigm((float)z2[1]);
    h.x = a0 * h.x + sqrtf(1.f - a0 * a0 + 1e-8f) * b2f(x2[0]);
    h.y = a1 * h.y + sqrtf(1.f - a1 * a1 + 1e-8f) * b2f(x2[1]);
    P.x *= a0; P.y *= a1;
  }
  ch_h[gtid] = h;
  ch_p[gtid] = P;
}

__global__ void scan_phase2(float2* __restrict__ ch_h, const float2* __restrict__ ch_p) {
  int pair = blockIdx.x * 256 + threadIdx.x;   // 4096 pairs
  float2 H = {0.f, 0.f};
#pragma unroll
  for (int c = 0; c < NCH; ++c) {
    int i = c * NPAIR + pair;
    float2 he = ch_h[i];
    float2 P  = ch_p[i];
    ch_h[i] = H;          // carry-in for this chunk
    H.x = he.x + P.x * H.x;
    H.y = he.y + P.y * H.y;
  }
}

// Phase 3: rescan with carry-in; y = gate*h written IN PLACE over gate.
__global__ void scan_phase3(const f16* __restrict__ z, const u16* __restrict__ xin,
                            u16* gate_y, const float2* __restrict__ ch_h) {
  int gtid = blockIdx.x * 256 + threadIdx.x;
  int c = gtid >> 12;
  int pair = gtid & (NPAIR - 1);
  int b = pair >> 10;
  int d = (pair & 1023) * 2;
  size_t base = ((size_t)b * TLEN + (size_t)c * CHUNK) * DREC + d;
  float2 h = ch_h[gtid];
#pragma unroll 8
  for (int t = 0; t < CHUNK; ++t) {
    size_t i = base + (size_t)t * DREC;
    f16 z2[2]; *(uint32_t*)z2 = *(const uint32_t*)(z + i);
    u16 x2[2]; *(uint32_t*)x2 = *(const uint32_t*)(xin + i);
    u16 g2[2]; *(uint32_t*)g2 = *(const uint32_t*)(gate_y + i);
    float a0 = sigm((float)z2[0]), a1 = sigm((float)z2[1]);
    h.x = a0 * h.x + sqrtf(1.f - a0 * a0 + 1e-8f) * b2f(x2[0]);
    h.y = a1 * h.y + sqrtf(1.f - a1 * a1 + 1e-8f) * b2f(x2[1]);
    u16 o2[2];
    o2[0] = f2bf(b2f(g2[0]) * h.x);
    o2[1] = f2bf(b2f(g2[1]) * h.y);
    *(uint32_t*)(gate_y + i) = *(uint32_t*)o2;
  }
}

// ---------------------------------------------------------------------------
extern "C" void kernel_launch(void* const* d_in, const int* in_sizes, int n_in,
                              void* d_out, int out_size, void* d_ws, size_t ws_size,
                              hipStream_t stream) {
  const float* x      = (const float*)d_in[0];
  const float* ln1    = (const float*)d_in[1];
  const float* ln2    = (const float*)d_in[2];
  const float* w_in   = (const float*)d_in[3];
  const float* w_gate = (const float*)d_in[4];
  const float* a_par  = (const float*)d_in[5];
  const float* w_a    = (const float*)d_in[6];
  const float* w_out  = (const float*)d_in[7];
  const float* w_mg   = (const float*)d_in[8];
  const float* w_mu   = (const float*)d_in[9];
  const float* w_md   = (const float*)d_in[10];
  float* out = (float*)d_out;
  char* ws = (char*)d_ws;

  const size_t MB = 1024ull * 1024ull;
  // bf16 weights: 0..44 MB
  u16* wb_in  = (u16*)(ws + 0 * MB);    // 4 MB  (dead after step 3)
  u16* wb_gt  = (u16*)(ws + 4 * MB);    // 4 MB  (dead after step 3)
  u16* wb_a   = (u16*)(ws + 8 * MB);    // 8 MB
  u16* wb_out = (u16*)(ws + 16 * MB);   // 4 MB
  u16* wb_mg  = (u16*)(ws + 20 * MB);   // 8 MB
  u16* wb_mu  = (u16*)(ws + 28 * MB);   // 8 MB
  u16* wb_md  = (u16*)(ws + 36 * MB);   // 8 MB
  // activations (time-multiplexed)
  u16* hbuf  = (u16*)(ws + 44 * MB);    // 32 MB: h, later h2
  f16* zbuf  = (f16*)(ws + 44 * MB);    // 64 MB: a-logits (over dead h)
  u16* gateb = (u16*)(ws + 108 * MB);   // 64 MB: gate -> y -> dead
  u16* mbuf  = (u16*)(ws + 108 * MB);   // 64 MB: mlp half (after y dead)
  // chunk summaries (2 MB each) overlay wb_in/wb_gt (dead once scan starts)
  float2* chh = (float2*)(ws + 0 * MB);
  float2* chp = (float2*)(ws + 2 * MB);
  u16* xinb = (u16*)d_out;              // d_out as scratch: xin, then xr
  // high-water: 173 MB of ws

  // 1) all weights -> bf16 in one launch
  f2b_all<<<22528, 256, 0, stream>>>(w_in, w_gate, w_a, w_out, w_mg, w_mu, w_md,
                                     wb_in, wb_gt, wb_a, wb_out, wb_mg, wb_mu, wb_md);

  // 2) h = rmsnorm(x, ln1)
  rmsnorm_kernel<<<BT, 256, 0, stream>>>(x, ln1, hbuf);

  // 3) fused: xin = h@w_in^T (raw, -> d_out), gate = sigmoid(h@w_gate^T)
  gemm2<EPI2_XG><<<dim3(BT / BM, DREC / 64), 256, 0, stream>>>(
      hbuf, wb_in, wb_gt, HID, DREC, HID, HID, xinb, gateb);

  // 4) z = a_param + xin@w_a^T  (fp16 logits)
  gemm1<EPI_LOGIT><<<dim3(BT / BM, DREC / BN), 256, 0, stream>>>(
      xinb, wb_a, DREC, DREC, DREC, DREC, nullptr, zbuf, a_par);

  // 5) chunked scan; y = gate*h in place over gate
  scan_phase1<<<NCH * NPAIR / 256, 256, 0, stream>>>(zbuf, xinb, chh, chp);
  scan_phase2<<<NPAIR / 256, 256, 0, stream>>>(chh, chp);
  scan_phase3<<<NCH * NPAIR / 256, 256, 0, stream>>>(zbuf, xinb, gateb, chh);

  // 6) xr = x + y@w_out^T  -> d_out (xin dead)
  gemm1<EPI_ADDF><<<dim3(BT / BM, HID / BN), 256, 0, stream>>>(
      gateb, wb_out, DREC, HID, DREC, DREC, out, nullptr, x);

  // 7) h2 = rmsnorm(xr, ln2)
  rmsnorm_kernel<<<BT, 256, 0, stream>>>(out, ln2, hbuf);

  // 8) MLP in two INTER halves; down-GEMM accumulates into d_out in place
  for (int half = 0; half < 2; ++half) {
    const u16* wmg_h = wb_mg + (size_t)half * 2048 * HID;
    const u16* wmu_h = wb_mu + (size_t)half * 2048 * HID;
    const u16* wmd_h = wb_md + (size_t)half * 2048;      // column slice, ldW=INTER
    gemm2<EPI2_SM><<<dim3(BT / BM, 2048 / 64), 256, 0, stream>>>(
        hbuf, wmg_h, wmu_h, HID, 2048, HID, HID, mbuf, nullptr);
    gemm1<EPI_ADDF><<<dim3(BT / BM, HID / BN), 256, 0, stream>>>(
        mbuf, wmd_h, 2048, HID, 2048, INTER, out, nullptr, out);
  }
}